// Round 3
// baseline (431.105 us; speedup 1.0000x reference)
//
#include <hip/hip_runtime.h>

#define TSTEPS 256
#define GROUP  8     // t-steps per pipelined load/compute batch

// non-temporal scalar load/store: every byte touched exactly once (zero-halo
// full-T sweep) -> bypass L2/LLC allocation for both streams
__device__ __forceinline__ float ntload1(const float* p) {
    return __builtin_nontemporal_load(p);
}
__device__ __forceinline__ void ntstore1(float* p, const float v) {
    __builtin_nontemporal_store(v, p);
}

// Zero-halo full-T sweep (minimum 512 MiB traffic) at float1 granularity:
// 262144 columns -> 4096 waves -> 4 waves/SIMD (vs 2 for float2, 1 for float4).
// Same bytes, 4 independent load/store streams per SIMD keep VMEM issue
// continuous. Coalescing unaffected: 64 lanes x 4B = full 256B segments.
__global__ __launch_bounds__(256) void tanhP1_kernel(
    const float* __restrict__ x,
    const float* __restrict__ c2, const float* __restrict__ c3,
    const float* __restrict__ c4, const float* __restrict__ c5,
    float* __restrict__ out, int N)
{
    // all 4 per-t constant bits in one float4 -> one broadcast ds_read_b128/step
    __shared__ float4 sbc[TSTEPS];
    const int tid = threadIdx.x;
    sbc[tid] = make_float4(c2[tid], c3[tid], c4[tid], c5[tid]);
    __syncthreads();

    const int j = blockIdx.x * blockDim.x + tid;    // scalar column index
    if (j >= N) return;

    const float* __restrict__ xc   = x + j;
    float* __restrict__       outc = out + j;
    const size_t stride = (size_t)N;

    // zero-initialized carry (t starts at 0 for every block)
    float xd[8];  // xd[k] = x[t-1-k]
    float m[3];   // m[k]  = n1[t-1-k]
    #pragma unroll
    for (int k = 0; k < 8; ++k) xd[k] = 0.f;
    #pragma unroll
    for (int k = 0; k < 3; ++k) m[k] = 0.f;

    // one group: consume 8 prefetched rows, store 8 output rows (nt)
    auto compute_group = [&](const float (&xt)[GROUP], int tg) {
        #pragma unroll
        for (int i = 0; i < GROUP; ++i) {
            const float4 c  = sbc[tg + i];
            const float n1 = xt[i] * xd[3];             // x[t] & x[t-4]
            const float n2 = 1.f - n1 * c.x;
            const float n3 = 1.f - n2 * c.y * m[0];
            const float n4 = 1.f - n3 * c.z * m[1];
            const float n5 = 1.f - n4 * c.w * m[2];
            ntstore1(&outc[(size_t)(tg + i) * stride], n5 * xd[7]);

            xd[7] = xd[6]; xd[6] = xd[5]; xd[5] = xd[4]; xd[4] = xd[3];
            xd[3] = xd[2]; xd[2] = xd[1]; xd[1] = xd[0]; xd[0] = xt[i];
            m[2] = m[1]; m[1] = m[0]; m[0] = n1;
        }
    };

    float bufA[GROUP], bufB[GROUP];

    // prime the pipeline: group 0 loads in flight
    #pragma unroll
    for (int i = 0; i < GROUP; ++i)
        bufA[i] = ntload1(&xc[(size_t)i * stride]);

    #pragma unroll 1
    for (int g = 0; g < TSTEPS; g += 2 * GROUP) {
        // prefetch group g+1 while group g's loads complete / compute runs
        {
            const int tp = g + GROUP;                // < TSTEPS, always valid
            #pragma unroll
            for (int i = 0; i < GROUP; ++i)
                bufB[i] = ntload1(&xc[(size_t)(tp + i) * stride]);
        }
        compute_group(bufA, g);

        // prefetch group g+2 (skip past the end)
        if (g + 2 * GROUP < TSTEPS) {
            const int tp = g + 2 * GROUP;
            #pragma unroll
            for (int i = 0; i < GROUP; ++i)
                bufA[i] = ntload1(&xc[(size_t)(tp + i) * stride]);
        }
        compute_group(bufB, g + GROUP);
    }
}

extern "C" void kernel_launch(void* const* d_in, const int* in_sizes, int n_in,
                              void* d_out, int out_size, void* d_ws, size_t ws_size,
                              hipStream_t stream) {
    const float* x  = (const float*)d_in[0];
    const float* c2 = (const float*)d_in[1];
    const float* c3 = (const float*)d_in[2];
    const float* c4 = (const float*)d_in[3];
    const float* c5 = (const float*)d_in[4];
    float* out = (float*)d_out;

    const int N = in_sizes[0] / TSTEPS;   // 262144 scalar columns

    dim3 block(256);
    dim3 grid(N / 256, 1);                // 1024 blocks = 4/CU, zero-halo full-T sweep
    tanhP1_kernel<<<grid, block, 0, stream>>>(x, c2, c3, c4, c5, out, N);
}

// Round 4
// 420.608 us; speedup vs baseline: 1.0250x; 1.0250x over previous
//
#include <hip/hip_runtime.h>

#define TSTEPS 256
#define GROUP  8     // t-steps per pipelined load/compute batch

typedef float v2f __attribute__((ext_vector_type(2)));

// non-temporal float2 load/store: every byte touched exactly once (zero-halo
// full-T sweep) -> bypass L2/LLC allocation for both streams
__device__ __forceinline__ float2 ntload2(const float2* p) {
    v2f v = __builtin_nontemporal_load((const v2f*)p);
    return make_float2(v.x, v.y);
}
__device__ __forceinline__ void ntstore2(float2* p, const float2 v) {
    v2f t = {v.x, v.y};
    __builtin_nontemporal_store(t, (v2f*)p);
}

// Zero-halo full-T sweep (minimum 512 MiB traffic) at float2 granularity —
// the measured optimum of the granularity sweep:
//   float4 / 1 wave/SIMD  -> ~97 us kernel (issue too bursty)
//   float2 / 2 waves/SIMD -> ~88 us kernel (~6.1 TB/s mixed R+W)  <== this
//   float1 / 4 waves/SIMD -> ~102 us kernel (VMEM instruction-rate-limited)
// 8 B/lane keeps 512 B per wave-instruction while 2 resident waves/SIMD keep
// VMEM issue continuous.
__global__ __launch_bounds__(256) void tanhP1_kernel(
    const float* __restrict__ x,
    const float* __restrict__ c2, const float* __restrict__ c3,
    const float* __restrict__ c4, const float* __restrict__ c5,
    float* __restrict__ out, int N2)
{
    // all 4 per-t constant bits in one float4 -> one broadcast ds_read_b128/step
    __shared__ float4 sbc[TSTEPS];
    const int tid = threadIdx.x;
    sbc[tid] = make_float4(c2[tid], c3[tid], c4[tid], c5[tid]);
    __syncthreads();

    const int j2 = blockIdx.x * blockDim.x + tid;   // float2 column index
    if (j2 >= N2) return;

    const float2* __restrict__ x2   = (const float2*)x + j2;
    float2* __restrict__       out2 = (float2*)out + j2;
    const size_t stride = (size_t)N2;

    // zero-initialized carry (t starts at 0 for every block)
    float2 xd[8];  // xd[k] = x[t-1-k]
    float2 m[3];   // m[k]  = n1[t-1-k]
    #pragma unroll
    for (int k = 0; k < 8; ++k) xd[k] = make_float2(0.f, 0.f);
    #pragma unroll
    for (int k = 0; k < 3; ++k) m[k] = make_float2(0.f, 0.f);

    // one group: consume 8 prefetched rows, store 8 output rows (nt)
    auto compute_group = [&](const float2 (&xt)[GROUP], int tg) {
        #pragma unroll
        for (int i = 0; i < GROUP; ++i) {
            const float4 c  = sbc[tg + i];
            const float2 n1 = make_float2(xt[i].x * xd[3].x, xt[i].y * xd[3].y);
            const float2 n2 = make_float2(1.f - n1.x * c.x, 1.f - n1.y * c.x);
            const float2 n3 = make_float2(1.f - n2.x * c.y * m[0].x,
                                          1.f - n2.y * c.y * m[0].y);
            const float2 n4 = make_float2(1.f - n3.x * c.z * m[1].x,
                                          1.f - n3.y * c.z * m[1].y);
            const float2 n5 = make_float2(1.f - n4.x * c.w * m[2].x,
                                          1.f - n4.y * c.w * m[2].y);
            ntstore2(&out2[(size_t)(tg + i) * stride],
                     make_float2(n5.x * xd[7].x, n5.y * xd[7].y));

            xd[7] = xd[6]; xd[6] = xd[5]; xd[5] = xd[4]; xd[4] = xd[3];
            xd[3] = xd[2]; xd[2] = xd[1]; xd[1] = xd[0]; xd[0] = xt[i];
            m[2] = m[1]; m[1] = m[0]; m[0] = n1;
        }
    };

    float2 bufA[GROUP], bufB[GROUP];

    // prime the pipeline: group 0 loads in flight
    #pragma unroll
    for (int i = 0; i < GROUP; ++i)
        bufA[i] = ntload2(&x2[(size_t)i * stride]);

    #pragma unroll 1
    for (int g = 0; g < TSTEPS; g += 2 * GROUP) {
        // prefetch group g+1 while group g's loads complete / compute runs
        {
            const int tp = g + GROUP;                // < TSTEPS, always valid
            #pragma unroll
            for (int i = 0; i < GROUP; ++i)
                bufB[i] = ntload2(&x2[(size_t)(tp + i) * stride]);
        }
        compute_group(bufA, g);

        // prefetch group g+2 (skip past the end)
        if (g + 2 * GROUP < TSTEPS) {
            const int tp = g + 2 * GROUP;
            #pragma unroll
            for (int i = 0; i < GROUP; ++i)
                bufA[i] = ntload2(&x2[(size_t)(tp + i) * stride]);
        }
        compute_group(bufB, g + GROUP);
    }
}

extern "C" void kernel_launch(void* const* d_in, const int* in_sizes, int n_in,
                              void* d_out, int out_size, void* d_ws, size_t ws_size,
                              hipStream_t stream) {
    const float* x  = (const float*)d_in[0];
    const float* c2 = (const float*)d_in[1];
    const float* c3 = (const float*)d_in[2];
    const float* c4 = (const float*)d_in[3];
    const float* c5 = (const float*)d_in[4];
    float* out = (float*)d_out;

    const int N  = in_sizes[0] / TSTEPS;  // 262144
    const int N2 = N / 2;                 // 131072 float2 columns

    dim3 block(256);
    dim3 grid(N2 / 256, 1);               // 512 blocks = 2/CU, zero-halo full-T sweep
    tanhP1_kernel<<<grid, block, 0, stream>>>(x, c2, c3, c4, c5, out, N2);
}